// Round 1
// baseline (9.619 us; speedup 1.0000x reference)
//
#include <hip/hip_runtime.h>
#include <hip/hip_bf16.h>

// Problem constants (from reference)
#define NEMBED    1000
#define EMBED_DIM 16
#define BATCH     16
#define NSET      24
#define DCH       17   // EMBED_DIM + 1

// pooled[b,d] = (sum_n x[b,n,d])^4 ; out[b] = sum_d pooled[b,d]*W[d] + bias
// One block per batch element, lane d (0..16) owns channel d.
__global__ void Eq4Net_kernel(const int* __restrict__ xcat,
                              const float* __restrict__ xfeat,
                              const float* __restrict__ embed,
                              const float* __restrict__ W,
                              const float* __restrict__ bias,
                              float* __restrict__ out) {
    const int b = blockIdx.x;
    const int d = threadIdx.x;   // 0..63, only 0..16 active

    float val = 0.0f;
    if (d < DCH) {
        float s = 0.0f;
        if (d < EMBED_DIM) {
            #pragma unroll
            for (int n = 0; n < NSET; ++n) {
                const int idx = xcat[b * NSET + n];
                const float e = embed[idx * EMBED_DIM + d];
                s += fmaxf(e, 0.0f);   // relu
            }
        } else {
            #pragma unroll
            for (int n = 0; n < NSET; ++n) {
                s += xfeat[b * NSET + n];
            }
        }
        const float s2 = s * s;
        val = s2 * s2 * W[d];
    }

    // wave-64 reduction (inactive lanes contribute 0)
    #pragma unroll
    for (int off = 32; off > 0; off >>= 1) {
        val += __shfl_down(val, off, 64);
    }

    if (d == 0) {
        out[b] = val + bias[0];
    }
}

extern "C" void kernel_launch(void* const* d_in, const int* in_sizes, int n_in,
                              void* d_out, int out_size, void* d_ws, size_t ws_size,
                              hipStream_t stream) {
    const int*   xcat  = (const int*)d_in[0];
    const float* xfeat = (const float*)d_in[1];
    const float* embed = (const float*)d_in[2];
    const float* W     = (const float*)d_in[3];
    const float* bias  = (const float*)d_in[4];
    float* out = (float*)d_out;

    Eq4Net_kernel<<<BATCH, 64, 0, stream>>>(xcat, xfeat, embed, W, bias, out);
}